// Round 6
// baseline (95.697 us; speedup 1.0000x reference)
//
#include <hip/hip_runtime.h>

#define B_ 8
#define T_ 2048
#define D_ 512
#define NTPB 272   /* tiles per batch: sum_{i=0..15} (2i+2) */

typedef float f32x16 __attribute__((ext_vector_type(16)));
typedef __bf16 bf16x8 __attribute__((ext_vector_type(8)));

// order-preserving float<->uint encoding for atomicMax on possibly-negative floats
__device__ __forceinline__ unsigned encf(float f) {
    int i = __float_as_int(f);
    return (i < 0) ? ~((unsigned)i) : (((unsigned)i) | 0x80000000u);
}
__device__ __forceinline__ float decf(unsigned u) {
    unsigned b = (u & 0x80000000u) ? (u ^ 0x80000000u) : ~u;
    return __int_as_float((int)b);
}

// Kernel 1: xn[row] = bf16(x[row] / max(||x[row]||,1e-12)); init msim to enc(-1)
__global__ __launch_bounds__(256) void rownorm_kernel(
        const float* __restrict__ x, __bf16* __restrict__ xn,
        unsigned* __restrict__ msim) {
    int row  = blockIdx.x * 4 + (threadIdx.x >> 6);
    int lane = threadIdx.x & 63;
    const float* p = x + (size_t)row * D_ + lane * 8;
    float4 a = *(const float4*)p;
    float4 b = *(const float4*)(p + 4);
    float ss = a.x*a.x + a.y*a.y + a.z*a.z + a.w*a.w
             + b.x*b.x + b.y*b.y + b.z*b.z + b.w*b.w;
#pragma unroll
    for (int m = 32; m; m >>= 1) ss += __shfl_xor(ss, m);
    float r = 1.0f / fmaxf(sqrtf(ss), 1e-12f);
    bf16x8 h;
    h[0] = (__bf16)(a.x * r); h[1] = (__bf16)(a.y * r);
    h[2] = (__bf16)(a.z * r); h[3] = (__bf16)(a.w * r);
    h[4] = (__bf16)(b.x * r); h[5] = (__bf16)(b.y * r);
    h[6] = (__bf16)(b.z * r); h[7] = (__bf16)(b.w * r);
    *(bf16x8*)(xn + (size_t)row * D_ + lane * 8) = h;
    if (lane == 0) msim[row] = 0x407FFFFFu;   // encf(-1.0f)
}

// Kernel 2: wave-autonomous. One 64-thread block = one wave = one 128x64
// output tile of the causal cosine-sim max. No LDS, no barriers: MFMA
// fragments loaded straight from global (L2) into VGPRs, double-buffered
// per 2-kstep group (64B/row contiguous reads). mfma_f32_32x32x16_bf16.
// Tile grid: rows in 128-chunks (i=0..15), cols in 64-chunks (j<=2i+1);
// j in {2i,2i+1} straddles the diagonal -> epilogue mask.
__global__ __launch_bounds__(64, 2) void simmax_kernel(
        const __bf16* __restrict__ xn, unsigned* __restrict__ msim) {
    int bid = blockIdx.x;
    int b   = bid & 7;        // batch -> XCD (round-robin dispatch)
    int t   = bid >> 3;       // 0..271
    int i = 0;
    while ((i + 1) * (i + 2) <= t) i++;
    int j = t - i * (i + 1);
    const bool strad = (j >= 2 * i);

    int ln = threadIdx.x;     // 0..63 (one wave)
    int lr = ln & 31;         // A-row / B-col / C-col within 32
    int hc = ln >> 5;         // k-half selector

    const char* xb = (const char*)xn;
    // byte offsets (xn is 16.8MB -> fits 32-bit)
    unsigned baseA = ((unsigned)(b * T_ + i * 128 + lr) * D_ + hc * 8) * 2;
    unsigned baseB = ((unsigned)(b * T_ + j * 64  + lr) * D_ + hc * 8) * 2;

    f32x16 acc[4][2];
#pragma unroll
    for (int mi = 0; mi < 4; mi++)
#pragma unroll
        for (int ni = 0; ni < 2; ni++)
#pragma unroll
            for (int r = 0; r < 16; r++)
                acc[mi][ni][r] = 0.f;

    // frag buffers: [buf][tile][k-half]; group g covers ksteps 2g,2g+1
    bf16x8 a[2][4][2], bb[2][2][2];

#define LOADG(buf, g) do {                                                  \
    _Pragma("unroll")                                                       \
    for (int mi = 0; mi < 4; mi++) {                                        \
        a[buf][mi][0] = *(const bf16x8*)(xb + baseA + mi * 32768 + (g) * 64);      \
        a[buf][mi][1] = *(const bf16x8*)(xb + baseA + mi * 32768 + (g) * 64 + 32); \
    }                                                                       \
    _Pragma("unroll")                                                       \
    for (int ni = 0; ni < 2; ni++) {                                        \
        bb[buf][ni][0] = *(const bf16x8*)(xb + baseB + ni * 32768 + (g) * 64);      \
        bb[buf][ni][1] = *(const bf16x8*)(xb + baseB + ni * 32768 + (g) * 64 + 32); \
    }                                                                       \
} while (0)

    LOADG(0, 0);
#pragma unroll
    for (int g = 0; g < 16; g++) {
        if (g < 15) LOADG((g + 1) & 1, g + 1);   // prefetch next group
#pragma unroll
        for (int h = 0; h < 2; h++)
#pragma unroll
            for (int mi = 0; mi < 4; mi++)
#pragma unroll
                for (int ni = 0; ni < 2; ni++)
                    acc[mi][ni] = __builtin_amdgcn_mfma_f32_32x32x16_bf16(
                        a[g & 1][mi][h], bb[g & 1][ni][h], acc[mi][ni], 0, 0, 0);
    }
#undef LOADG

    // epilogue: C/D layout (m74/m101): col = lane&31,
    // row = (reg&3) + 8*(reg>>2) + 4*(lane>>5)
    unsigned* mbase = msim + (size_t)b * T_ + (size_t)i * 128;
    const float NINF = -__builtin_inff();
    int gcol0 = j * 64 + lr;          // + ni*32
#pragma unroll
    for (int mi = 0; mi < 4; mi++) {
#pragma unroll
        for (int r = 0; r < 16; r++) {
            int rloc = mi * 32 + (r & 3) + 8 * (r >> 2) + 4 * hc;
            int grow = i * 128 + rloc;
            float t0 = acc[mi][0][r];
            float t1 = acc[mi][1][r];
            if (strad) {
                if (gcol0      >= grow) t0 = NINF;
                if (gcol0 + 32 >= grow) t1 = NINF;
            }
            float v = fmaxf(t0, t1);
            v = fmaxf(v, __shfl_xor(v, 1));
            v = fmaxf(v, __shfl_xor(v, 2));
            v = fmaxf(v, __shfl_xor(v, 4));
            v = fmaxf(v, __shfl_xor(v, 8));
            v = fmaxf(v, __shfl_xor(v, 16));
            if (lr == 0) atomicMax(&mbase[rloc], encf(v));
        }
    }
}

// Kernel 3: out = gelu_tanh(x * (1-alpha + alpha*exp(-tau*max_sim)))
__global__ __launch_bounds__(256) void gelu_kernel(
        const float* __restrict__ x, const unsigned* __restrict__ msim,
        const float* __restrict__ ltau, const float* __restrict__ lblend,
        float* __restrict__ out) {
    int i = blockIdx.x * 256 + threadIdx.x;   // float4 index
    float tau   = __expf(ltau[0]);
    float alpha = 1.f / (1.f + __expf(-lblend[0]));
    int row = i >> 7;                          // D_/4 = 128 float4 per row
    float ms = decf(msim[row]);
    float sc = (1.f - alpha) + alpha * __expf(-tau * ms);
    float4 v = ((const float4*)x)[i];
    const float c0 = 0.7978845608028654f;
    const float c1 = 0.044715f;
    float4 o;
#pragma unroll
    for (int k = 0; k < 4; k++) {
        float z = ((const float*)&v)[k] * sc;
        float u = c0 * (z + c1 * z * z * z);
        float e = __expf(2.f * u);
        float th = 1.f - 2.f / (e + 1.f);      // tanh, inf-safe
        ((float*)&o)[k] = 0.5f * z * (1.f + th);
    }
    ((float4*)out)[i] = o;
}

extern "C" void kernel_launch(void* const* d_in, const int* in_sizes, int n_in,
                              void* d_out, int out_size, void* d_ws, size_t ws_size,
                              hipStream_t stream) {
    (void)in_sizes; (void)n_in; (void)out_size; (void)ws_size;
    const float* x      = (const float*)d_in[0];
    const float* ltau   = (const float*)d_in[1];
    const float* lblend = (const float*)d_in[2];
    float*    out   = (float*)d_out;
    // xn (16.8 MB) lives in d_out until gelu overwrites it; msim in ws.
    __bf16*   xn    = (__bf16*)d_out;
    unsigned* msim  = (unsigned*)d_ws;

    rownorm_kernel<<<B_ * T_ / 4, 256, 0, stream>>>(x, xn, msim);
    simmax_kernel<<<B_ * NTPB, 64, 0, stream>>>(xn, msim);
    gelu_kernel<<<(B_ * T_ * D_ / 4) / 256, 256, 0, stream>>>(x, msim, ltau, lblend, out);
}